// Round 6
// baseline (421.366 us; speedup 1.0000x reference)
//
#include <hip/hip_runtime.h>
#include <hip/hip_bf16.h>

#define B_   4
#define L_   1024
#define D_   1280
#define H_   20
#define DH_  64
#define BH_  (B_*H_)     // 80
#define L2_  (2*L_)      // 2048
#define ALPHA_ 0.48f

typedef __attribute__((ext_vector_type(8))) short short8;
typedef __attribute__((ext_vector_type(4))) float float4v;

__device__ __forceinline__ float bf2f(ushort u) {
    union { unsigned int i; float f; } v; v.i = ((unsigned int)u) << 16; return v.f;
}
__device__ __forceinline__ ushort f2bf(float f) {
    union { float f; unsigned int i; } v; v.f = f;
    unsigned int i = v.i;
    unsigned int r = i + 0x7FFF + ((i >> 16) & 1);  // RNE
    return (ushort)(r >> 16);
}
__device__ __forceinline__ short8 pack8(float4 f0, float4 f1) {
    short8 o;
    o[0] = (short)f2bf(f0.x); o[1] = (short)f2bf(f0.y);
    o[2] = (short)f2bf(f0.z); o[3] = (short)f2bf(f0.w);
    o[4] = (short)f2bf(f1.x); o[5] = (short)f2bf(f1.y);
    o[6] = (short)f2bf(f1.z); o[7] = (short)f2bf(f1.w);
    return o;
}
// pack 4 f32 -> 4 bf16 (RNE) and store as one 8-byte write
__device__ __forceinline__ void pack4_store(ushort* dst, float a, float b, float c, float d) {
    union { __hip_bfloat162 h; unsigned int u; } x, y;
    x.h = __float22bfloat162_rn(make_float2(a, b));
    y.h = __float22bfloat162_rn(make_float2(c, d));
    uint2 v; v.x = x.u; v.y = y.u;
    *(uint2*)dst = v;
}

// async global->LDS, 16 B per lane; dest = wave-uniform base + lane*16
__device__ __forceinline__ void async16(const void* g, void* l) {
    __builtin_amdgcn_global_load_lds(
        (__attribute__((address_space(1))) void*)g,
        (__attribute__((address_space(3))) void*)l, 16, 0, 0);
}

// ---------------- dtype detector: flag=1 if storage is bf16, 0 if f32 ----------------
__global__ __launch_bounds__(256) void detect_dtype(const unsigned int* __restrict__ w,
                                                    int* __restrict__ flag) {
    __shared__ int cnt;
    if (threadIdx.x == 0) cnt = 0;
    __syncthreads();
    int local = 0;
    for (int i = threadIdx.x; i < 4096; i += 256) {
        unsigned e = (w[i] >> 7) & 0xFF;
        local += (e >= 100 && e <= 130) ? 1 : 0;
    }
    atomicAdd(&cnt, local);
    __syncthreads();
    if (threadIdx.x == 0) flag[0] = (cnt > 2048) ? 1 : 0;
}

// ---------------- fused prep: weight transposes + alpha*V_bg transpose + f32 converts
// bi <  1600 : transpose4  (z=bi/400): Wt[z][c][r] = w_z[r][c]
// bi <  2880 : stage_vbg   : Vt[bh][d][1024+kv] = ALPHA * Vbg[bh][kv][d]
// bi <  5440 : cvt_x  (f32 input only): Xb = bf16(X)
// bi <  8000 : cvt_kbg (f32 input only): Kcv = bf16(Kbg)
__global__ __launch_bounds__(256) void prep(
    const void* __restrict__ w0, const void* __restrict__ w1,
    const void* __restrict__ w2, const void* __restrict__ w3,
    ushort* __restrict__ Wt,
    const void* __restrict__ Vbg, ushort* __restrict__ Vt,
    const void* __restrict__ X, ushort* __restrict__ Xb,
    const void* __restrict__ Kbg, ushort* __restrict__ Kcv,
    const int* __restrict__ flag) {
    bool is16 = flag[0] != 0;
    int bi = blockIdx.x, tid = threadIdx.x;
    if (bi < 2880) {
        bool doScale = (bi >= 1600);
        const void* src; ushort* dst; int srcld, dstld; long sbase, dbase;
        if (bi < 1600) {
            int z = bi / 400, t4 = bi % 400;
            int by = t4 / 20, bx = t4 % 20;
            const void* srcs[4] = {w0, w1, w2, w3};
            src = srcs[z]; srcld = D_; dstld = D_;
            sbase = (long)(by * 64) * D_ + bx * 64;
            dst = Wt + (long)z * D_ * D_;
            dbase = (long)(bx * 64) * D_ + by * 64;
        } else {
            int j = bi - 1600;          // 0..1279
            int bh = j >> 4, kt = j & 15;
            src = Vbg; srcld = DH_; dstld = L2_;
            sbase = ((long)bh * L_ + kt * 64) * DH_;
            dst = Vt;
            dbase = (long)bh * DH_ * L2_ + L_ + kt * 64;
        }
        __shared__ ushort t[64 * 72];
        int ldr = tid >> 3, ldc = (tid & 7) * 8;
#pragma unroll
        for (int i = 0; i < 2; i++) {
            int y = ldr + 32 * i;
            long idx = sbase + (long)y * srcld + ldc;
            short8 v;
            if (is16) {
                v = *(const short8*)((const ushort*)src + idx);
                if (doScale) {
#pragma unroll
                    for (int j2 = 0; j2 < 8; j2++)
                        v[j2] = (short)f2bf(ALPHA_ * bf2f((ushort)v[j2]));
                }
            } else {
                const float* s = (const float*)src;
                float4 f0 = *(const float4*)&s[idx];
                float4 f1 = *(const float4*)&s[idx + 4];
                if (doScale) {
                    f0.x *= ALPHA_; f0.y *= ALPHA_; f0.z *= ALPHA_; f0.w *= ALPHA_;
                    f1.x *= ALPHA_; f1.y *= ALPHA_; f1.z *= ALPHA_; f1.w *= ALPHA_;
                }
                v = pack8(f0, f1);
            }
            *(short8*)&t[y * 72 + ldc] = v;
        }
        __syncthreads();
        int c = tid & 63, r0 = (tid >> 6) * 16;
#pragma unroll
        for (int i = 0; i < 2; i++) {
            short8 o;
#pragma unroll
            for (int j2 = 0; j2 < 8; j2++) o[j2] = (short)t[(r0 + i * 8 + j2) * 72 + c];
            *(short8*)&dst[dbase + (long)c * dstld + r0 + i * 8] = o;
        }
    } else if (bi < 5440) {
        if (is16) return;
        long i = ((long)(bi - 2880) * 256 + tid) * 8;
        const float* s = (const float*)X;
        *(short8*)&Xb[i] = pack8(*(const float4*)&s[i], *(const float4*)&s[i + 4]);
    } else {
        if (is16) return;
        long i = ((long)(bi - 5440) * 256 + tid) * 8;
        const float* s = (const float*)Kbg;
        *(short8*)&Kcv[i] = pack8(*(const float4*)&s[i], *(const float4*)&s[i + 4]);
    }
}

// ---------------- GEMM (bf16): C[m][n] = sum_k A[m][k]*Bt[n][k], K=1280 --------------
// m97-style: global_load_lds width=16 staging into unpadded [row][32] LDS tiles.
// mode 0: A = (flag? Araw : A16); scatter -> Qp (x0.125), Kp, Vt (packed b64, transposed)
// mode 1: A = A16 (Ctx); Out = acc + bo[n] (out dtype per flag)
template<int BMt, int BNt, int WROWS, int WCOLS>
__global__ __launch_bounds__(256) void gemm_tpl(
    const ushort* __restrict__ A16, const void* __restrict__ Araw,
    const ushort* __restrict__ Bt,
    ushort* __restrict__ Qp, ushort* __restrict__ Kp, ushort* __restrict__ Vt,
    void* __restrict__ Out, const void* __restrict__ bo, int mode,
    const int* __restrict__ flag) {
    constexpr int MI = BMt / WROWS / 16;
    constexpr int NI = BNt / WCOLS / 16;
    __shared__ __align__(16) ushort Al[BMt * 32];
    __shared__ __align__(16) ushort Bl[BNt * 32];
    bool is16 = flag[0] != 0;
    const ushort* A = (mode == 0 && is16) ? (const ushort*)Araw : A16;
    int tid = threadIdx.x;
    int bx = blockIdx.x, by = blockIdx.y;
    int w = tid >> 6, lane = tid & 63, l15 = lane & 15, quad = lane >> 4;
    int wm = (w / WCOLS) * (BMt / WROWS);
    int wn = (w % WCOLS) * (BNt / WCOLS);
    float4v acc[MI][NI] = {};
    const int K = 1280;
    const ushort* Arow = A + (long)by * BMt * K + (tid >> 2) * K + (tid & 3) * 8;
    const ushort* Brow = Bt + (long)bx * BNt * K + (tid >> 2) * K + (tid & 3) * 8;

    for (int kb = 0; kb < K; kb += 32) {
        __syncthreads();
#pragma unroll
        for (int i = 0; i < BMt / 64; i++)
            async16(Arow + (long)i * 64 * K + kb, &Al[(i * 4 + w) * 512]);
#pragma unroll
        for (int i = 0; i < BNt / 64; i++)
            async16(Brow + (long)i * 64 * K + kb, &Bl[(i * 4 + w) * 512]);
        __syncthreads();  // drains vmcnt -> staged data visible
        short8 av[MI], bv[NI];
#pragma unroll
        for (int mi = 0; mi < MI; mi++)
            av[mi] = *(const short8*)&Al[(wm + mi * 16 + l15) * 32 + quad * 8];
#pragma unroll
        for (int ni = 0; ni < NI; ni++)
            bv[ni] = *(const short8*)&Bl[(wn + ni * 16 + l15) * 32 + quad * 8];
#pragma unroll
        for (int mi = 0; mi < MI; mi++)
#pragma unroll
            for (int ni = 0; ni < NI; ni++)
                acc[mi][ni] = __builtin_amdgcn_mfma_f32_16x16x32_bf16(av[mi], bv[ni], acc[mi][ni], 0, 0, 0);
    }

    if (mode == 0) {
        int which = bx / 10;  // block-uniform: n-range of a block stays in one region
#pragma unroll
        for (int mi = 0; mi < MI; mi++) {
            int m0 = by * BMt + wm + mi * 16 + quad * 4;
            int b = m0 >> 10, l0 = m0 & 1023;
#pragma unroll
            for (int ni = 0; ni < NI; ni++) {
                int n = bx * BNt + wn + ni * 16 + l15;
                int np = n - which * 1280;
                int h = np >> 6, dh = np & 63;
                if (which == 0) {
#pragma unroll
                    for (int r = 0; r < 4; r++)
                        Qp[((long)(b * H_ + h) * L_ + l0 + r) * DH_ + dh] =
                            f2bf(acc[mi][ni][r] * 0.125f);
                } else if (which == 1) {
#pragma unroll
                    for (int r = 0; r < 4; r++)
                        Kp[((long)(b * H_ + h) * L_ + l0 + r) * DH_ + dh] =
                            f2bf(acc[mi][ni][r]);
                } else {
                    pack4_store(&Vt[((long)(b * H_ + h) * DH_ + dh) * L2_ + l0],
                                acc[mi][ni][0], acc[mi][ni][1],
                                acc[mi][ni][2], acc[mi][ni][3]);
                }
            }
        }
    } else {
#pragma unroll
        for (int mi = 0; mi < MI; mi++) {
            int mloc = wm + mi * 16 + quad * 4;
#pragma unroll
            for (int ni = 0; ni < NI; ni++) {
                int nloc = wn + ni * 16 + l15;
#pragma unroll
                for (int r = 0; r < 4; r++) {
                    int m = by * BMt + mloc + r;
                    int n = bx * BNt + nloc;
                    float bias = is16 ? bf2f(((const ushort*)bo)[n]) : ((const float*)bo)[n];
                    float o = acc[mi][ni][r] + bias;
                    if (is16) ((ushort*)Out)[(long)m * D_ + n] = f2bf(o);
                    else      ((float*)Out)[(long)m * D_ + n] = o;
                }
            }
        }
    }
}

// ---------------- flash attention: barrier-free, direct-from-L2 fragments ------------
// Un-shifted softmax (scores bounded; exp fp32-safe) == reference softmax.
// S^T via MFMA(A=K,B=Q): lane holds q=l15, kv=quad*4+r  -> rs is lane-local in q,
// P store is 4-contiguous (b64), Ctx store is 4-contiguous (8B packed).
// alpha: scores *= alpha for bg keys (== q.(alpha K_bg)); V_bg pre-scaled in prep.
// K/V frags load DIRECTLY from global (L2-resident, 25 MB working set, XCD swizzle);
// no __syncthreads anywhere -> no barrier drains; Pl is per-wave rows only.
#define FS 72  // Pl row stride (elems): 144 B, 16B-aligned, uniform bank spread

__global__ __launch_bounds__(256) void flash_attn(
    const ushort* __restrict__ Qp, const ushort* __restrict__ Kp,
    const void* __restrict__ KbgRaw, const ushort* __restrict__ Kcv,
    const ushort* __restrict__ Vt, ushort* __restrict__ Ctx,
    const int* __restrict__ flag) {
    __shared__ __align__(16) ushort Pl[128 * FS];
    const ushort* Kbg = flag[0] ? (const ushort*)KbgRaw : Kcv;
    int tid = threadIdx.x;
    int w = tid >> 6, lane = tid & 63, l15 = lane & 15, quad = lane >> 4;
    int bi = blockIdx.x;
    int bh = (bi & 7) * 10 + ((bi >> 3) % 10);
    int qt = bi / 80;

    // Q fragments: direct global b128 loads (loop-invariant)
    short8 aq[2][2];
    const ushort* Qb = Qp + ((long)bh * L_ + qt * 128 + w * 32) * DH_;
#pragma unroll
    for (int mi = 0; mi < 2; mi++)
#pragma unroll
        for (int ks = 0; ks < 2; ks++)
            aq[mi][ks] = *(const short8*)&Qb[(mi * 16 + l15) * DH_ + ks * 32 + quad * 8];

    float rs[2] = {0.f, 0.f};
    float4v O[2][4] = {};
    const ushort* Vb = Vt + (long)bh * DH_ * L2_;
    int prow = (w * 32 + l15) * FS;  // wave-private Pl rows [w*32, w*32+32)

    for (int kt = 0; kt < 32; kt++) {
        const ushort* Ksrc = (kt < 16)
            ? Kp  + ((long)bh * L_ + kt * 64) * DH_
            : Kbg + ((long)bh * L_ + (kt - 16) * 64) * DH_;
        bool bg = (kt >= 16);
        // K and V fragments straight from global (per-lane b128)
        short8 bk[2][4], bv[2][4];
#pragma unroll
        for (int ks = 0; ks < 2; ks++)
#pragma unroll
            for (int nt = 0; nt < 4; nt++) {
                bk[ks][nt] = *(const short8*)&Ksrc[(nt * 16 + l15) * DH_ + ks * 32 + quad * 8];
                bv[ks][nt] = *(const short8*)&Vb[(long)(nt * 16 + l15) * L2_ + kt * 64 + ks * 32 + quad * 8];
            }
#pragma unroll
        for (int mi = 0; mi < 2; mi++) {
            // S^T = MFMA(A=K, B=Q): lane q = w*32+mi*16+l15, kv = nt*16+quad*4+r
            float4v s[4] = {};
#pragma unroll
            for (int ks = 0; ks < 2; ks++)
#pragma unroll
                for (int nt = 0; nt < 4; nt++)
                    s[nt] = __builtin_amdgcn_mfma_f32_16x16x32_bf16(bk[ks][nt], aq[mi][ks], s[nt], 0, 0, 0);
#pragma unroll
            for (int nt = 0; nt < 4; nt++) {
                float p[4];
#pragma unroll
                for (int r = 0; r < 4; r++) {
                    float sv = s[nt][r];
                    if (bg) sv *= ALPHA_;
                    p[r] = __expf(sv);
                    rs[mi] += p[r];
                }
                pack4_store(&Pl[prow + mi * 16 * FS + nt * 16 + quad * 4],
                            p[0], p[1], p[2], p[3]);
            }
        }
        // per-wave LDS write->read ordering (no cross-wave sharing of Pl rows)
        asm volatile("s_waitcnt lgkmcnt(0)\n" ::: "memory");
        // O^T += MFMA(A=V^T, B=P): lane q = l15, d = nt*16+quad*4+r
#pragma unroll
        for (int mi = 0; mi < 2; mi++)
#pragma unroll
            for (int ks = 0; ks < 2; ks++) {
                short8 ap = *(const short8*)&Pl[prow + mi * 16 * FS + ks * 32 + quad * 8];
#pragma unroll
                for (int nt = 0; nt < 4; nt++)
                    O[mi][nt] = __builtin_amdgcn_mfma_f32_16x16x32_bf16(bv[ks][nt], ap, O[mi][nt], 0, 0, 0);
            }
    }
    // rs lives at q=l15 in all 4 quads' partials: reduce across quads (2 shuffles)
    float rcp[2];
#pragma unroll
    for (int mi = 0; mi < 2; mi++) {
        float v = rs[mi];
        v += __shfl_xor(v, 16);
        v += __shfl_xor(v, 32);
        rcp[mi] = 1.f / v;
    }
    // Ctx[b*L+l][h*64+dh]: lane has l = ...+l15 fixed, dh = nt*16+quad*4+r -> packed 8B
    int b = bh / H_, h = bh % H_;
#pragma unroll
    for (int mi = 0; mi < 2; mi++) {
        long l = qt * 128 + w * 32 + mi * 16 + l15;
#pragma unroll
        for (int nt = 0; nt < 4; nt++)
            pack4_store(&Ctx[(long)(b * L_ + l) * D_ + h * DH_ + nt * 16 + quad * 4],
                        O[mi][nt][0] * rcp[mi], O[mi][nt][1] * rcp[mi],
                        O[mi][nt][2] * rcp[mi], O[mi][nt][3] * rcp[mi]);
    }
}

extern "C" void kernel_launch(void* const* d_in, const int* in_sizes, int n_in,
                              void* d_out, int out_size, void* d_ws, size_t ws_size,
                              hipStream_t stream) {
    const void* X   = d_in[0];
    const void* Wq  = d_in[1];
    const void* Wk  = d_in[2];
    const void* Wv  = d_in[3];
    const void* Wo  = d_in[4];
    const void* bo  = d_in[5];
    const void* Kbg = d_in[6];
    const void* Vbg = d_in[7];

    char* ws = (char*)d_ws;
    size_t off = 0;
    auto alloc = [&](size_t bytes) {
        void* p = ws + off;
        off = (off + bytes + 255) & ~(size_t)255;
        return p;
    };
    int*    dflag = (int*)alloc(256);
    ushort* Wt    = (ushort*)alloc((size_t)4 * D_ * D_ * 2);     // Wq^T|Wk^T|Wv^T|Wo^T
    ushort* Qp    = (ushort*)alloc((size_t)BH_ * L_ * DH_ * 2);
    ushort* Kp    = (ushort*)alloc((size_t)BH_ * L_ * DH_ * 2);
    ushort* Kcv   = (ushort*)alloc((size_t)BH_ * L_ * DH_ * 2);  // bf16(Kbg), f32 path
    ushort* Vt    = (ushort*)alloc((size_t)BH_ * DH_ * L2_ * 2); // [V^T ; alpha V_bg^T]
    ushort* Xb    = (ushort*)alloc((size_t)B_ * L_ * D_ * 2);    // bf16(X), f32 path
    ushort* Ctx   = Xb;  // Xb dead after QKV GEMM; flash writes Ctx afterwards
    ushort* Wqkv_t = Wt;
    ushort* Wo_t   = Wt + (size_t)3 * D_ * D_;

    dim3 tb(256);
    detect_dtype<<<1, tb, 0, stream>>>((const unsigned int*)Wq, dflag);
    prep<<<8000, tb, 0, stream>>>(Wq, Wk, Wv, Wo, Wt, Vbg, Vt, X, Xb, Kbg, Kcv, dflag);
    // QKV projection: N = 3840 (Q|K|V), M = 4096
    gemm_tpl<128, 128, 2, 2><<<dim3(30, 32), tb, 0, stream>>>(
        Xb, X, Wqkv_t, Qp, Kp, Vt, nullptr, nullptr, 0, dflag);
    // attention: 640 blocks, XCD-swizzled, barrier-free
    flash_attn<<<dim3(640), tb, 0, stream>>>(Qp, Kp, Kbg, Kcv, Vt, Ctx, dflag);
    // output projection
    gemm_tpl<64, 128, 1, 4><<<dim3(10, 64), tb, 0, stream>>>(
        Ctx, nullptr, Wo_t, nullptr, nullptr, nullptr, d_out, bo, 1, dflag);
}

// Round 7
// 332.424 us; speedup vs baseline: 1.2676x; 1.2676x over previous
//
#include <hip/hip_runtime.h>
#include <hip/hip_bf16.h>

#define B_   4
#define L_   1024
#define D_   1280
#define H_   20
#define DH_  64
#define BH_  (B_*H_)     // 80
#define L2_  (2*L_)      // 2048
#define ALPHA_ 0.48f

typedef __attribute__((ext_vector_type(8))) short short8;
typedef __attribute__((ext_vector_type(4))) float float4v;

__device__ __forceinline__ float bf2f(ushort u) {
    union { unsigned int i; float f; } v; v.i = ((unsigned int)u) << 16; return v.f;
}
__device__ __forceinline__ ushort f2bf(float f) {
    union { float f; unsigned int i; } v; v.f = f;
    unsigned int i = v.i;
    unsigned int r = i + 0x7FFF + ((i >> 16) & 1);  // RNE
    return (ushort)(r >> 16);
}
__device__ __forceinline__ short8 pack8(float4 f0, float4 f1) {
    short8 o;
    o[0] = (short)f2bf(f0.x); o[1] = (short)f2bf(f0.y);
    o[2] = (short)f2bf(f0.z); o[3] = (short)f2bf(f0.w);
    o[4] = (short)f2bf(f1.x); o[5] = (short)f2bf(f1.y);
    o[6] = (short)f2bf(f1.z); o[7] = (short)f2bf(f1.w);
    return o;
}
// pack 4 f32 -> 4 bf16 (RNE, v_cvt_pk) and store as one 8-byte write
__device__ __forceinline__ void pack4_store(ushort* dst, float a, float b, float c, float d) {
    union { __hip_bfloat162 h; unsigned int u; } x, y;
    x.h = __float22bfloat162_rn(make_float2(a, b));
    y.h = __float22bfloat162_rn(make_float2(c, d));
    uint2 v; v.x = x.u; v.y = y.u;
    *(uint2*)dst = v;
}

// async global->LDS, 16 B per lane; dest = wave-uniform base + lane*16
__device__ __forceinline__ void async16(const void* g, void* l) {
    __builtin_amdgcn_global_load_lds(
        (__attribute__((address_space(1))) void*)g,
        (__attribute__((address_space(3))) void*)l, 16, 0, 0);
}

// ---------------- dtype detector: flag=1 if storage is bf16, 0 if f32 ----------------
__global__ __launch_bounds__(256) void detect_dtype(const unsigned int* __restrict__ w,
                                                    int* __restrict__ flag) {
    __shared__ int cnt;
    if (threadIdx.x == 0) cnt = 0;
    __syncthreads();
    int local = 0;
    for (int i = threadIdx.x; i < 4096; i += 256) {
        unsigned e = (w[i] >> 7) & 0xFF;
        local += (e >= 100 && e <= 130) ? 1 : 0;
    }
    atomicAdd(&cnt, local);
    __syncthreads();
    if (threadIdx.x == 0) flag[0] = (cnt > 2048) ? 1 : 0;
}

// ---------------- fused prep: weight transposes + alpha*V_bg transpose + f32 converts
// bi <  1600 : transpose4  (z=bi/400): Wt[z][c][r] = w_z[r][c]
// bi <  2880 : stage_vbg   : Vt[bh][d][1024+kv] = ALPHA * Vbg[bh][kv][d]
// bi <  5440 : cvt_x  (f32 input only): Xb = bf16(X)
// bi <  8000 : cvt_kbg (f32 input only): Kcv = bf16(Kbg)
__global__ __launch_bounds__(256) void prep(
    const void* __restrict__ w0, const void* __restrict__ w1,
    const void* __restrict__ w2, const void* __restrict__ w3,
    ushort* __restrict__ Wt,
    const void* __restrict__ Vbg, ushort* __restrict__ Vt,
    const void* __restrict__ X, ushort* __restrict__ Xb,
    const void* __restrict__ Kbg, ushort* __restrict__ Kcv,
    const int* __restrict__ flag) {
    bool is16 = flag[0] != 0;
    int bi = blockIdx.x, tid = threadIdx.x;
    if (bi < 2880) {
        bool doScale = (bi >= 1600);
        const void* src; ushort* dst; int srcld, dstld; long sbase, dbase;
        if (bi < 1600) {
            int z = bi / 400, t4 = bi % 400;
            int by = t4 / 20, bx = t4 % 20;
            const void* srcs[4] = {w0, w1, w2, w3};
            src = srcs[z]; srcld = D_; dstld = D_;
            sbase = (long)(by * 64) * D_ + bx * 64;
            dst = Wt + (long)z * D_ * D_;
            dbase = (long)(bx * 64) * D_ + by * 64;
        } else {
            int j = bi - 1600;          // 0..1279
            int bh = j >> 4, kt = j & 15;
            src = Vbg; srcld = DH_; dstld = L2_;
            sbase = ((long)bh * L_ + kt * 64) * DH_;
            dst = Vt;
            dbase = (long)bh * DH_ * L2_ + L_ + kt * 64;
        }
        __shared__ ushort t[64 * 72];
        int ldr = tid >> 3, ldc = (tid & 7) * 8;
#pragma unroll
        for (int i = 0; i < 2; i++) {
            int y = ldr + 32 * i;
            long idx = sbase + (long)y * srcld + ldc;
            short8 v;
            if (is16) {
                v = *(const short8*)((const ushort*)src + idx);
                if (doScale) {
#pragma unroll
                    for (int j2 = 0; j2 < 8; j2++)
                        v[j2] = (short)f2bf(ALPHA_ * bf2f((ushort)v[j2]));
                }
            } else {
                const float* s = (const float*)src;
                float4 f0 = *(const float4*)&s[idx];
                float4 f1 = *(const float4*)&s[idx + 4];
                if (doScale) {
                    f0.x *= ALPHA_; f0.y *= ALPHA_; f0.z *= ALPHA_; f0.w *= ALPHA_;
                    f1.x *= ALPHA_; f1.y *= ALPHA_; f1.z *= ALPHA_; f1.w *= ALPHA_;
                }
                v = pack8(f0, f1);
            }
            *(short8*)&t[y * 72 + ldc] = v;
        }
        __syncthreads();
        int c = tid & 63, r0 = (tid >> 6) * 16;
#pragma unroll
        for (int i = 0; i < 2; i++) {
            short8 o;
#pragma unroll
            for (int j2 = 0; j2 < 8; j2++) o[j2] = (short)t[(r0 + i * 8 + j2) * 72 + c];
            *(short8*)&dst[dbase + (long)c * dstld + r0 + i * 8] = o;
        }
    } else if (bi < 5440) {
        if (is16) return;
        long i = ((long)(bi - 2880) * 256 + tid) * 8;
        const float* s = (const float*)X;
        *(short8*)&Xb[i] = pack8(*(const float4*)&s[i], *(const float4*)&s[i + 4]);
    } else {
        if (is16) return;
        long i = ((long)(bi - 5440) * 256 + tid) * 8;
        const float* s = (const float*)Kbg;
        *(short8*)&Kcv[i] = pack8(*(const float4*)&s[i], *(const float4*)&s[i + 4]);
    }
}

// ---------------- GEMM (bf16): C[m][n] = sum_k A[m][k]*Bt[n][k], K=1280 --------------
// Double-buffered async LDS staging, ONE barrier per K-iter: stage ki+1 into the idle
// buffer, compute ki, then __syncthreads (drains vmcnt for the prefetch + fences reuse).
// mode 0: A = (flag? Araw : A16); scatter -> Qp (x0.125), Kp, Vt (packed b64, transposed)
// mode 1: A = A16 (Ctx); Out = acc + bo[n] (out dtype per flag)
template<int BMt, int BNt, int WROWS, int WCOLS>
__global__ __launch_bounds__(256) void gemm_tpl(
    const ushort* __restrict__ A16, const void* __restrict__ Araw,
    const ushort* __restrict__ Bt,
    ushort* __restrict__ Qp, ushort* __restrict__ Kp, ushort* __restrict__ Vt,
    void* __restrict__ Out, const void* __restrict__ bo, int mode,
    const int* __restrict__ flag) {
    constexpr int MI = BMt / WROWS / 16;
    constexpr int NI = BNt / WCOLS / 16;
    constexpr int ASZ = BMt * 32, BSZ = BNt * 32;
    __shared__ __align__(16) ushort Al[2 * ASZ];
    __shared__ __align__(16) ushort Bl[2 * BSZ];
    bool is16 = flag[0] != 0;
    const ushort* A = (mode == 0 && is16) ? (const ushort*)Araw : A16;
    int tid = threadIdx.x;
    int bx = blockIdx.x, by = blockIdx.y;
    int w = tid >> 6, lane = tid & 63, l15 = lane & 15, quad = lane >> 4;
    int wm = (w / WCOLS) * (BMt / WROWS);
    int wn = (w % WCOLS) * (BNt / WCOLS);
    float4v acc[MI][NI] = {};
    const int K = 1280;
    constexpr int NK = 40;
    const ushort* Arow = A + (long)by * BMt * K + (tid >> 2) * K + (tid & 3) * 8;
    const ushort* Brow = Bt + (long)bx * BNt * K + (tid >> 2) * K + (tid & 3) * 8;

    auto stage = [&](int ki, int b) {
#pragma unroll
        for (int i = 0; i < BMt / 64; i++)
            async16(Arow + (long)i * 64 * K + ki * 32, &Al[b * ASZ + (i * 4 + w) * 512]);
#pragma unroll
        for (int i = 0; i < BNt / 64; i++)
            async16(Brow + (long)i * 64 * K + ki * 32, &Bl[b * BSZ + (i * 4 + w) * 512]);
    };

    stage(0, 0);
    __syncthreads();
    for (int ki = 0; ki < NK; ki++) {
        int cur = ki & 1;
        if (ki + 1 < NK) stage(ki + 1, 1 - cur);
        short8 av[MI], bv[NI];
#pragma unroll
        for (int mi = 0; mi < MI; mi++)
            av[mi] = *(const short8*)&Al[cur * ASZ + (wm + mi * 16 + l15) * 32 + quad * 8];
#pragma unroll
        for (int ni = 0; ni < NI; ni++)
            bv[ni] = *(const short8*)&Bl[cur * BSZ + (wn + ni * 16 + l15) * 32 + quad * 8];
#pragma unroll
        for (int mi = 0; mi < MI; mi++)
#pragma unroll
            for (int ni = 0; ni < NI; ni++)
                acc[mi][ni] = __builtin_amdgcn_mfma_f32_16x16x32_bf16(av[mi], bv[ni], acc[mi][ni], 0, 0, 0);
        __syncthreads();  // prefetch complete + all waves done with cur buffer
    }

    if (mode == 0) {
        int which = bx / 10;  // block-uniform: n-range of a block stays in one region
#pragma unroll
        for (int mi = 0; mi < MI; mi++) {
            int m0 = by * BMt + wm + mi * 16 + quad * 4;
            int b = m0 >> 10, l0 = m0 & 1023;
#pragma unroll
            for (int ni = 0; ni < NI; ni++) {
                int n = bx * BNt + wn + ni * 16 + l15;
                int np = n - which * 1280;
                int h = np >> 6, dh = np & 63;
                if (which == 0) {
#pragma unroll
                    for (int r = 0; r < 4; r++)
                        Qp[((long)(b * H_ + h) * L_ + l0 + r) * DH_ + dh] =
                            f2bf(acc[mi][ni][r] * 0.125f);
                } else if (which == 1) {
#pragma unroll
                    for (int r = 0; r < 4; r++)
                        Kp[((long)(b * H_ + h) * L_ + l0 + r) * DH_ + dh] =
                            f2bf(acc[mi][ni][r]);
                } else {
                    pack4_store(&Vt[((long)(b * H_ + h) * DH_ + dh) * L2_ + l0],
                                acc[mi][ni][0], acc[mi][ni][1],
                                acc[mi][ni][2], acc[mi][ni][3]);
                }
            }
        }
    } else {
#pragma unroll
        for (int mi = 0; mi < MI; mi++) {
            int mloc = wm + mi * 16 + quad * 4;
#pragma unroll
            for (int ni = 0; ni < NI; ni++) {
                int nloc = wn + ni * 16 + l15;
#pragma unroll
                for (int r = 0; r < 4; r++) {
                    int m = by * BMt + mloc + r;
                    int n = bx * BNt + nloc;
                    float bias = is16 ? bf2f(((const ushort*)bo)[n]) : ((const float*)bo)[n];
                    float o = acc[mi][ni][r] + bias;
                    if (is16) ((ushort*)Out)[(long)m * D_ + n] = f2bf(o);
                    else      ((float*)Out)[(long)m * D_ + n] = o;
                }
            }
        }
    }
}

// ---------------- flash attention: LDS-staged K/V (dbuf, 1 barrier/kt) ---------------
// Un-shifted softmax (scores bounded; exp fp32-safe) == reference softmax.
// S^T via MFMA(A=K,B=Q): lane holds q=l15, kv=quad*4+r -> rs lane-local,
// P store packed b64, Ctx store packed 8B.  (Transposed math verified in R6.)
// alpha: scores *= alpha for bg keys; V_bg pre-scaled by alpha in prep.
// K/V double-buffered: stage kt+1 while computing kt; one __syncthreads per kt.
#define FS 72  // Pl row stride (elems): 144 B, 16B-aligned, 2-way banks only

__global__ __launch_bounds__(256) void flash_attn(
    const ushort* __restrict__ Qp, const ushort* __restrict__ Kp,
    const void* __restrict__ KbgRaw, const ushort* __restrict__ Kcv,
    const ushort* __restrict__ Vt, ushort* __restrict__ Ctx,
    const int* __restrict__ flag) {
    __shared__ __align__(16) ushort Kl[2 * 4096], Vl[2 * 4096];
    __shared__ __align__(16) ushort Pl[128 * FS];
    const ushort* Kbg = flag[0] ? (const ushort*)KbgRaw : Kcv;
    int tid = threadIdx.x;
    int w = tid >> 6, lane = tid & 63, l15 = lane & 15, quad = lane >> 4;
    int bi = blockIdx.x;
    int bh = (bi & 7) * 10 + ((bi >> 3) % 10);
    int qt = bi / 80;

    // Q fragments: direct global b128 loads (loop-invariant, one-time)
    short8 aq[2][2];
    const ushort* Qb = Qp + ((long)bh * L_ + qt * 128 + w * 32) * DH_;
#pragma unroll
    for (int mi = 0; mi < 2; mi++)
#pragma unroll
        for (int ks = 0; ks < 2; ks++)
            aq[mi][ks] = *(const short8*)&Qb[(mi * 16 + l15) * DH_ + ks * 32 + quad * 8];

    float rs[2] = {0.f, 0.f};
    float4v O[2][4] = {};
    const ushort* Vb = Vt + (long)bh * DH_ * L2_;
    int prow = (w * 32 + l15) * FS;  // wave-private Pl rows [w*32, w*32+32)

    auto stage = [&](int kt, int b) {
        const ushort* Ksrc = (kt < 16)
            ? Kp  + ((long)bh * L_ + kt * 64) * DH_
            : Kbg + ((long)bh * L_ + (kt - 16) * 64) * DH_;
#pragma unroll
        for (int i = 0; i < 2; i++) {
            int q = i * 4 + w;
            async16(&Ksrc[(long)lane * DH_ + q * 8], &Kl[b * 4096 + q * 512]);
            async16(&Vb[(long)lane * L2_ + kt * 64 + q * 8], &Vl[b * 4096 + q * 512]);
        }
    };

    stage(0, 0);
    __syncthreads();
    for (int kt = 0; kt < 32; kt++) {
        int cur = kt & 1;
        if (kt + 1 < 32) stage(kt + 1, 1 - cur);
        bool bg = (kt >= 16);
        // K fragments from LDS (chunk-major: [chunk q][row][8])
        short8 bk[2][4];
#pragma unroll
        for (int ks = 0; ks < 2; ks++)
#pragma unroll
            for (int nt = 0; nt < 4; nt++)
                bk[ks][nt] = *(const short8*)&Kl[cur * 4096 + (ks * 4 + quad) * 512 + (nt * 16 + l15) * 8];
#pragma unroll
        for (int mi = 0; mi < 2; mi++) {
            // S^T = MFMA(A=K, B=Q): lane q = w*32+mi*16+l15, kv = nt*16+quad*4+r
            float4v s[4] = {};
#pragma unroll
            for (int ks = 0; ks < 2; ks++)
#pragma unroll
                for (int nt = 0; nt < 4; nt++)
                    s[nt] = __builtin_amdgcn_mfma_f32_16x16x32_bf16(bk[ks][nt], aq[mi][ks], s[nt], 0, 0, 0);
#pragma unroll
            for (int nt = 0; nt < 4; nt++) {
                float p[4];
#pragma unroll
                for (int r = 0; r < 4; r++) {
                    float sv = s[nt][r];
                    if (bg) sv *= ALPHA_;
                    p[r] = __expf(sv);
                    rs[mi] += p[r];
                }
                pack4_store(&Pl[prow + mi * 16 * FS + nt * 16 + quad * 4],
                            p[0], p[1], p[2], p[3]);
            }
        }
        // V fragments from LDS
        short8 bv[2][4];
#pragma unroll
        for (int ks = 0; ks < 2; ks++)
#pragma unroll
            for (int nt = 0; nt < 4; nt++)
                bv[ks][nt] = *(const short8*)&Vl[cur * 4096 + (ks * 4 + quad) * 512 + (nt * 16 + l15) * 8];
        // per-wave LDS write->read ordering for Pl (wave-private rows)
        asm volatile("s_waitcnt lgkmcnt(0)\n" ::: "memory");
        // O^T += MFMA(A=V^T, B=P): lane q = l15, d = nt*16+quad*4+r
#pragma unroll
        for (int mi = 0; mi < 2; mi++)
#pragma unroll
            for (int ks = 0; ks < 2; ks++) {
                short8 ap = *(const short8*)&Pl[prow + mi * 16 * FS + ks * 32 + quad * 8];
#pragma unroll
                for (int nt = 0; nt < 4; nt++)
                    O[mi][nt] = __builtin_amdgcn_mfma_f32_16x16x32_bf16(bv[ks][nt], ap, O[mi][nt], 0, 0, 0);
            }
        __syncthreads();  // prefetch complete + all waves done with cur buffer
    }
    // rs partials live across the 4 quads of each q: reduce with 2 shuffles
    float rcp[2];
#pragma unroll
    for (int mi = 0; mi < 2; mi++) {
        float v = rs[mi];
        v += __shfl_xor(v, 16);
        v += __shfl_xor(v, 32);
        rcp[mi] = 1.f / v;
    }
    // Ctx[b*L+l][h*64+dh]: lane has l fixed (l15), dh = nt*16+quad*4+r -> packed 8B
    int b = bh / H_, h = bh % H_;
#pragma unroll
    for (int mi = 0; mi < 2; mi++) {
        long l = qt * 128 + w * 32 + mi * 16 + l15;
#pragma unroll
        for (int nt = 0; nt < 4; nt++)
            pack4_store(&Ctx[(long)(b * L_ + l) * D_ + h * DH_ + nt * 16 + quad * 4],
                        O[mi][nt][0] * rcp[mi], O[mi][nt][1] * rcp[mi],
                        O[mi][nt][2] * rcp[mi], O[mi][nt][3] * rcp[mi]);
    }
}

extern "C" void kernel_launch(void* const* d_in, const int* in_sizes, int n_in,
                              void* d_out, int out_size, void* d_ws, size_t ws_size,
                              hipStream_t stream) {
    const void* X   = d_in[0];
    const void* Wq  = d_in[1];
    const void* Wk  = d_in[2];
    const void* Wv  = d_in[3];
    const void* Wo  = d_in[4];
    const void* bo  = d_in[5];
    const void* Kbg = d_in[6];
    const void* Vbg = d_in[7];

    char* ws = (char*)d_ws;
    size_t off = 0;
    auto alloc = [&](size_t bytes) {
        void* p = ws + off;
        off = (off + bytes + 255) & ~(size_t)255;
        return p;
    };
    int*    dflag = (int*)alloc(256);
    ushort* Wt    = (ushort*)alloc((size_t)4 * D_ * D_ * 2);     // Wq^T|Wk^T|Wv^T|Wo^T
    ushort* Qp    = (ushort*)alloc((size_t)BH_ * L_ * DH_ * 2);
    ushort* Kp    = (ushort*)alloc((size_t)BH_ * L_ * DH_ * 2);
    ushort* Kcv   = (ushort*)alloc((size_t)BH_ * L_ * DH_ * 2);  // bf16(Kbg), f32 path
    ushort* Vt    = (ushort*)alloc((size_t)BH_ * DH_ * L2_ * 2); // [V^T ; alpha V_bg^T]
    ushort* Xb    = (ushort*)alloc((size_t)B_ * L_ * D_ * 2);    // bf16(X), f32 path
    ushort* Ctx   = Xb;  // Xb dead after QKV GEMM; flash writes Ctx afterwards
    ushort* Wqkv_t = Wt;
    ushort* Wo_t   = Wt + (size_t)3 * D_ * D_;

    dim3 tb(256);
    detect_dtype<<<1, tb, 0, stream>>>((const unsigned int*)Wq, dflag);
    prep<<<8000, tb, 0, stream>>>(Wq, Wk, Wv, Wo, Wt, Vbg, Vt, X, Xb, Kbg, Kcv, dflag);
    // QKV projection: N = 3840 (Q|K|V), M = 4096
    gemm_tpl<128, 128, 2, 2><<<dim3(30, 32), tb, 0, stream>>>(
        Xb, X, Wqkv_t, Qp, Kp, Vt, nullptr, nullptr, 0, dflag);
    // attention: 640 blocks, XCD-swizzled, double-buffered
    flash_attn<<<dim3(640), tb, 0, stream>>>(Qp, Kp, Kbg, Kcv, Vt, Ctx, dflag);
    // output projection
    gemm_tpl<64, 128, 1, 4><<<dim3(10, 64), tb, 0, stream>>>(
        Ctx, nullptr, Wo_t, nullptr, nullptr, nullptr, d_out, bo, 1, dflag);
}